// Round 16
// baseline (4567.897 us; speedup 1.0000x reference)
//
#include <hip/hip_runtime.h>
#include <stdint.h>

#define B_  64
#define S_  512
#define E_  256
#define H_  512

typedef float  f32x4  __attribute__((ext_vector_type(4)));
typedef __bf16 bf16x8 __attribute__((ext_vector_type(8)));
typedef unsigned long long u64t;

__device__ __forceinline__ unsigned short f2b(float f) {
  uint32_t u = __builtin_bit_cast(uint32_t, f);
  uint32_t r = (u + 0x7FFFu + ((u >> 16) & 1u)) >> 16;
  return (unsigned short)r;
}
__device__ __forceinline__ float b2f(unsigned short s) {
  uint32_t u = ((uint32_t)s) << 16;
  return __builtin_bit_cast(float, u);
}
__device__ __forceinline__ bf16x8 ld_bf8(const unsigned short* p) {
  uint4 v = *reinterpret_cast<const uint4*>(p);
  return __builtin_bit_cast(bf16x8, v);
}

// ---------------- convert emb + W_ih to bf16 ----------------
__global__ void convert_kernel(const float* __restrict__ emb,
                               const float* __restrict__ wih,
                               unsigned short* __restrict__ emb_b,
                               unsigned short* __restrict__ wih_b) {
  const int64_t EMB_N = (int64_t)32000 * 256;
  const int64_t TOT8  = (EMB_N + (int64_t)1536 * 256) / 8;
  for (int64_t i8 = (int64_t)blockIdx.x * blockDim.x + threadIdx.x; i8 < TOT8;
       i8 += (int64_t)gridDim.x * blockDim.x) {
    int64_t e = i8 * 8;
    const float* src; unsigned short* dst;
    if (e < EMB_N) { src = emb + e;           dst = emb_b + e; }
    else           { src = wih + (e - EMB_N); dst = wih_b + (e - EMB_N); }
    float4 a = *reinterpret_cast<const float4*>(src);
    float4 b = *reinterpret_cast<const float4*>(src + 4);
    uint4 o;
    o.x = (unsigned)f2b(a.x) | ((unsigned)f2b(a.y) << 16);
    o.y = (unsigned)f2b(a.z) | ((unsigned)f2b(a.w) << 16);
    o.z = (unsigned)f2b(b.x) | ((unsigned)f2b(b.y) << 16);
    o.w = (unsigned)f2b(b.z) | ((unsigned)f2b(b.w) << 16);
    *reinterpret_cast<uint4*>(dst) = o;
  }
}

// ---------------- sequence lengths ----------------
__global__ void lengths_kernel(const int* __restrict__ x, int* __restrict__ len) {
  __shared__ int part[8];
  int b = blockIdx.x, tid = threadIdx.x;
  int v = (x[b * S_ + tid] != 0) ? 1 : 0;
  unsigned long long m = __ballot(v);
  if ((tid & 63) == 0) part[tid >> 6] = __popcll(m);
  __syncthreads();
  if (tid == 0) {
    int s = 0;
    #pragma unroll
    for (int i = 0; i < 8; ++i) s += part[i];
    len[b] = s;
  }
}

// -------- init exchange: parity0 = {tag 0 | h=0}, parity1 = {tag ~0} --------
__global__ void init_kernel(u64t* __restrict__ x64) {
  int i = blockIdx.x * blockDim.x + threadIdx.x;   // 128 x 256
  u64t v = (i < 16384) ? 0ull : 0xFFFFFFFF00000000ull;
  __hip_atomic_store(x64 + i, v, __ATOMIC_RELAXED, __HIP_MEMORY_SCOPE_AGENT);
}

// ---------------- phase 1: gi = emb[x] @ W_ih^T + b_ih (R5 layout) ----------
__global__ __launch_bounds__(256) void gi_kernel(
    const int* __restrict__ x, const unsigned short* __restrict__ emb_b,
    const unsigned short* __restrict__ wih_b, const float* __restrict__ b_ih,
    unsigned short* __restrict__ gi) {
  int tblk = blockIdx.x, g = blockIdx.y, w = blockIdx.z;
  int tid = threadIdx.x;
  int wv = tid >> 6, lane = tid & 63;
  int c16 = lane & 15, kq = lane >> 4;
  int t0 = tblk * 8 + wv, t1 = t0 + 4;

  int grow[6]; float bias[6];
  #pragma unroll
  for (int nt = 0; nt < 6; ++nt) {
    grow[nt] = (nt >> 1) * H_ + w * 32 + (nt & 1) * 16 + c16;
    bias[nt] = b_ih[grow[nt]];
  }
  int tok0 = x[(g * 16 + c16) * S_ + t0];
  int tok1 = x[(g * 16 + c16) * S_ + t1];

  f32x4 acc[2][6];
  #pragma unroll
  for (int nt = 0; nt < 6; ++nt) {
    acc[0][nt] = f32x4{bias[nt], bias[nt], bias[nt], bias[nt]};
    acc[1][nt] = acc[0][nt];
  }
  #pragma unroll
  for (int kk = 0; kk < 8; ++kk) {
    int kb = kk * 32 + kq * 8;
    bf16x8 A0 = ld_bf8(emb_b + (size_t)tok0 * E_ + kb);
    bf16x8 A1 = ld_bf8(emb_b + (size_t)tok1 * E_ + kb);
    #pragma unroll
    for (int nt = 0; nt < 6; ++nt) {
      bf16x8 Bf = ld_bf8(wih_b + (size_t)grow[nt] * E_ + kb);
      acc[0][nt] = __builtin_amdgcn_mfma_f32_16x16x32_bf16(A0, Bf, acc[0][nt], 0, 0, 0);
      acc[1][nt] = __builtin_amdgcn_mfma_f32_16x16x32_bf16(A1, Bf, acc[1][nt], 0, 0, 0);
    }
  }
  int wg = g * 16 + w;
  #pragma unroll
  for (int m = 0; m < 2; ++m) {
    int t = m ? t1 : t0;
    size_t base = ((size_t)(t * 64 + wg) * 16) * 96;
    #pragma unroll
    for (int nt = 0; nt < 6; ++nt)
      #pragma unroll
      for (int j = 0; j < 4; ++j)
        gi[base + (size_t)(kq * 4 + j) * 96 + nt * 16 + c16] = f2b(acc[m][nt][j]);
  }
}

// ---------------- phase 2: persistent GRU scan --------------------------------
// R11 protocol (tag-in-data u64 {step|2xbf16}, designated pollers, LDS
// broadcast), with two compiler-safe refinements:
//  (1) software-pipelined poll in pure C: two named 16xu64 load-sets via
//      __hip_atomic_load; set B is issued BEFORE checking set A. The compiler
//      inserts the required waitcnts (worst case: degenerates to R11's
//      stop-and-wait, still correct).
//  (2) poller waves = 8-11, gate waves = 0-7 (disjoint): pollers skip phase C
//      and jump from barrier2 straight to polling step t+1, so they are
//      already spinning when the last producer's store lands.
__global__ __launch_bounds__(768, 1) void scan_kernel(
    const float* __restrict__ whh, const float* __restrict__ b_hh,
    const unsigned short* __restrict__ gi, const int* __restrict__ len,
    u64t* __restrict__ xchg64, float* __restrict__ out) {
  __shared__ float gh[2][16 * 100];      // 12.8 KB
  __shared__ float hown[16 * 32];        //  2 KB
  __shared__ uint4 frag4[2][1024];       // 32 KB

  const int wgid = blockIdx.x, g = wgid >> 4, w = wgid & 15;
  const int tid = threadIdx.x, wv = tid >> 6, lane = tid & 63;
  const int nt = wv % 6, kh = wv / 6;
  const int c16 = lane & 15, kq = lane >> 4;

  const int grow = (nt >> 1) * H_ + w * 32 + (nt & 1) * 16 + c16;
  bf16x8 Bf[8];
  #pragma unroll
  for (int kk = 0; kk < 8; ++kk) {
    int kb = kh * 256 + kk * 32 + kq * 8;
    const float* p = whh + (size_t)grow * H_ + kb;
    float4 a = *reinterpret_cast<const float4*>(p);
    float4 b = *reinterpret_cast<const float4*>(p + 4);
    uint4 v;
    v.x = (unsigned)f2b(a.x) | ((unsigned)f2b(a.y) << 16);
    v.y = (unsigned)f2b(a.z) | ((unsigned)f2b(a.w) << 16);
    v.z = (unsigned)f2b(b.x) | ((unsigned)f2b(b.y) << 16);
    v.w = (unsigned)f2b(b.z) | ((unsigned)f2b(b.w) << 16);
    Bf[kk] = __builtin_bit_cast(bf16x8, v);
  }
  const float bhh_v = (kh == 0) ? b_hh[grow] : 0.0f;

  if (tid < 512) hown[tid] = 0.0f;
  const int i_e = (tid >> 5) & 15, c_e = tid & 31;
  const int lenv = len[g * 16 + i_e];
  int tmax = 0;
  for (int bi = 0; bi < 16; ++bi) {
    int l = len[g * 16 + bi];
    tmax = l > tmax ? l : tmax;
  }

  // poller geometry (waves 8-11): row = lane&15, colrun = (wv-8)*4 + (lane>>4)
  const int prow = lane & 15, pcolrun = (wv - 8) * 4 + (lane >> 4);
  const int fbase = pcolrun * 4;          // == ((pkh*8+pkk))*4, pcolrun = kh*8+kk
  __syncthreads();

  for (int t = 0; t < tmax; ++t) {
    const int p = t & 1;
    float i_r = 0.f, i_z = 0.f, i_n = 0.f;
    if (tid < 512) {   // gi prefetch — only gate waves need it
      size_t gib = ((size_t)(t * 64 + wgid) * 16 + i_e) * 96;
      i_r = b2f(gi[gib + c_e]);
      i_z = b2f(gi[gib + 32 + c_e]);
      i_n = b2f(gi[gib + 64 + c_e]);
    }

    // ---- phase A: waves 8-11 pipelined-poll h(t), broadcast to LDS ----
    if (wv >= 8) {
      const u64t* pw = xchg64 + (size_t)((p * 4 + g) * 16 + prow) * 256 +
                       pcolrun * 16;
      const uint32_t etag = (uint32_t)t;
      u64t A[16], Bv[16];
      #pragma unroll
      for (int j = 0; j < 16; ++j)
        A[j] = __hip_atomic_load(pw + j, __ATOMIC_RELAXED,
                                 __HIP_MEMORY_SCOPE_AGENT);
      bool useA = true;
      int s = 0;
      for (;;) {
        #pragma unroll
        for (int j = 0; j < 16; ++j)
          Bv[j] = __hip_atomic_load(pw + j, __ATOMIC_RELAXED,
                                    __HIP_MEMORY_SCOPE_AGENT);
        bool ok = true;
        #pragma unroll
        for (int j = 0; j < 16; ++j) ok &= ((uint32_t)(A[j] >> 32) == etag);
        if (__all(ok) || ++s >= (1 << 16)) { useA = true; break; }
        #pragma unroll
        for (int j = 0; j < 16; ++j)
          A[j] = __hip_atomic_load(pw + j, __ATOMIC_RELAXED,
                                   __HIP_MEMORY_SCOPE_AGENT);
        ok = true;
        #pragma unroll
        for (int j = 0; j < 16; ++j) ok &= ((uint32_t)(Bv[j] >> 32) == etag);
        if (__all(ok) || ++s >= (1 << 16)) { useA = false; break; }
      }
      #pragma unroll
      for (int q = 0; q < 4; ++q) {
        uint4 fa = uint4{(uint32_t)A[4 * q],     (uint32_t)A[4 * q + 1],
                         (uint32_t)A[4 * q + 2], (uint32_t)A[4 * q + 3]};
        uint4 fb = uint4{(uint32_t)Bv[4 * q],     (uint32_t)Bv[4 * q + 1],
                         (uint32_t)Bv[4 * q + 2], (uint32_t)Bv[4 * q + 3]};
        frag4[p][(fbase + q) * 16 + prow] = useA ? fa : fb;
      }
    }
    __syncthreads();

    // ---- phase B: MFMA from LDS fragments (all 12 waves) ----
    f32x4 acc = f32x4{bhh_v, bhh_v, bhh_v, bhh_v};
    #pragma unroll
    for (int kk = 0; kk < 8; ++kk) {
      uint4 af = frag4[p][((kh * 8 + kk) * 4 + kq) * 16 + c16];
      acc = __builtin_amdgcn_mfma_f32_16x16x32_bf16(
          __builtin_bit_cast(bf16x8, af), Bf[kk], acc, 0, 0, 0);
    }
    float* ghp = gh[kh];
    #pragma unroll
    for (int j = 0; j < 4; ++j)
      ghp[(kq * 4 + j) * 100 + nt * 16 + c16] = acc[j];
    __syncthreads();

    // ---- phase C: gate waves 0-7 compute gates + publish h(t+1) ----
    // poller waves skip this and immediately start polling step t+1.
    if (tid < 512) {
      float gr_ = gh[0][i_e * 100 + c_e]      + gh[1][i_e * 100 + c_e];
      float gz_ = gh[0][i_e * 100 + 32 + c_e] + gh[1][i_e * 100 + 32 + c_e];
      float gn_ = gh[0][i_e * 100 + 64 + c_e] + gh[1][i_e * 100 + 64 + c_e];
      float hp = hown[i_e * 32 + c_e];
      float r = 1.0f / (1.0f + __expf(-(i_r + gr_)));
      float z = 1.0f / (1.0f + __expf(-(i_z + gz_)));
      float pre = i_n + r * gn_;
      float e2 = __expf(2.0f * pre);
      float n = 1.0f - 2.0f / (e2 + 1.0f);
      float hn = z * (hp - n) + n;
      hown[i_e * 32 + c_e] = hn;
      unsigned short hb = f2b(hn);
      unsigned nb = (unsigned)__shfl_down((int)hb, 1) & 0xFFFFu;
      if ((c_e & 1) == 0) {
        u64t pack = ((u64t)(uint32_t)(t + 1) << 32) | ((u64t)nb << 16) | hb;
        u64t* dst = xchg64 + (size_t)((((t + 1) & 1) * 4 + g) * 16 + i_e) * 256 +
                    w * 16 + (c_e >> 1);
        __hip_atomic_store(dst, pack, __ATOMIC_RELAXED,
                           __HIP_MEMORY_SCOPE_AGENT);
      }
      if (t + 1 == lenv) out[(size_t)(g * 16 + i_e) * H_ + w * 32 + c_e] = hn;
    }
    // no trailing barrier: next step's poll is the transitive completion proof
  }
}

extern "C" void kernel_launch(void* const* d_in, const int* in_sizes, int n_in,
                              void* d_out, int out_size, void* d_ws, size_t ws_size,
                              hipStream_t stream) {
  const int*   x    = (const int*)d_in[0];
  const float* emb  = (const float*)d_in[1];
  const float* wih  = (const float*)d_in[2];
  const float* whh  = (const float*)d_in[3];
  const float* b_ih = (const float*)d_in[4];
  const float* b_hh = (const float*)d_in[5];
  float* out = (float*)d_out;

  char* ws = (char*)d_ws;
  const size_t GI_SZ    = (size_t)512 * 64 * 16 * 96 * 2;   // 100,663,296
  const size_t EMB_SZ   = (size_t)32000 * 256 * 2;          // 16,384,000
  const size_t WIH_SZ   = (size_t)1536 * 256 * 2;           //    786,432
  const size_t XCHG_SZ  = (size_t)32768 * 8;                //    262,144
  const size_t LEN_SZ   = 256;
  const size_t GI_OFF   = 0;
  const size_t EMB_OFF  = GI_OFF + GI_SZ;
  const size_t WIH_OFF  = EMB_OFF + EMB_SZ;
  const size_t XCHG_OFF = WIH_OFF + WIH_SZ;
  const size_t LEN_OFF  = XCHG_OFF + XCHG_SZ;
  if (ws_size < LEN_OFF + LEN_SZ) return;   // ~118 MB of scratch

  unsigned short* gi_p  = (unsigned short*)(ws + GI_OFF);
  unsigned short* emb_b = (unsigned short*)(ws + EMB_OFF);
  unsigned short* wih_b = (unsigned short*)(ws + WIH_OFF);
  u64t*           xchg  = (u64t*)(ws + XCHG_OFF);
  int*            len   = (int*)(ws + LEN_OFF);

  init_kernel<<<128, 256, 0, stream>>>(xchg);
  convert_kernel<<<2048, 256, 0, stream>>>(emb, wih, emb_b, wih_b);
  lengths_kernel<<<64, 512, 0, stream>>>(x, len);
  gi_kernel<<<dim3(64, 4, 16), 256, 0, stream>>>(x, emb_b, wih_b, b_ih, gi_p);
  scan_kernel<<<64, 768, 0, stream>>>(whh, b_hh, gi_p, len, xchg, out);
}